// Round 9
// baseline (701.603 us; speedup 1.0000x reference)
//
#include <hip/hip_runtime.h>
#include <stdint.h>

typedef __attribute__((ext_vector_type(8))) short short8;
typedef __attribute__((ext_vector_type(4))) float f32x4;
typedef __attribute__((ext_vector_type(2))) unsigned int u32x2;
typedef unsigned short u16;
typedef unsigned int u32;
typedef const __attribute__((address_space(1))) void gas_void;
typedef __attribute__((address_space(3))) void las_void;

#define NPER 6
#define NPANEL 50
#define WS_WELE (NPANEL * 8192)   // 50 pre-swizzled 16KB panels; h16 follows

__device__ inline u16 f2b(float f){                 // f32 -> bf16 (RNE)
  u32 u = __builtin_bit_cast(u32, f);
  u = u + 0x7FFFu + ((u >> 16) & 1u);
  return (u16)(u >> 16);
}
__device__ inline float b2f(u16 v){ return __builtin_bit_cast(float, ((u32)v) << 16); }
__device__ inline float elu1(float x){ return x > 0.f ? x : (__expf(x) - 1.f); }
__device__ inline u32 packbf(float a, float b){ return (u32)f2b(a) | ((u32)f2b(b) << 16); }

// ---- phase-ordered, PRE-SWIZZLED weight panels (identical to R7/R8) ----
__global__ __launch_bounds__(256) void convert_weights(
    const float* __restrict__ sw, const float* __restrict__ crw, const float* __restrict__ cw1,
    const float* __restrict__ cw2, const float* __restrict__ trw, const float* __restrict__ tw1,
    const float* __restrict__ tw2, u16* __restrict__ ws){
  int i = blockIdx.x * 256 + threadIdx.x;
  if (i >= WS_WELE) return;
  int p = i >> 13, e = i & 8191;
  float v;
  if (p == 32 || p == 49){
    int n = e >> 8, kc = e & 255;
    int ks = (kc & 7) | ((((kc >> 3) ^ (n & 7)) & 31) << 3);
    const float* w2 = (p == 32) ? cw2 : tw2;
    v = (n < NPER) ? w2[n * 256 + ks] : 0.f;
  } else {
    int n = e >> 5, kk = e & 31;
    int ks = (kk & 7) | ((((kk >> 3) ^ ((n >> 1) & 3)) & 3) << 3);
    if (p < 16){ v = sw[n * 512 + p * 32 + ks]; }
    else {
      const float* src; int kb;
      if (p < 24)      { src = crw; kb = (p - 16) * 32; }
      else if (p < 32) { src = cw1; kb = (p - 24) * 32; }
      else if (p < 41) { src = trw; kb = (p - 33) * 32; }
      else             { src = tw1; kb = (p - 41) * 32; }
      v = src[n * 256 + kb + ks];
    }
  }
  ws[i] = f2b(v);
}

__global__ __launch_bounds__(256) void convert_h(
    const float* __restrict__ h, u16* __restrict__ h16, int n8){
  int i = blockIdx.x * 256 + threadIdx.x;
  if (i >= n8) return;
  const float4* src = (const float4*)(h + (size_t)i * 8);
  float4 q0 = src[0], q1 = src[1];
  short8 v;
  v[0]=(short)f2b(q0.x); v[1]=(short)f2b(q0.y); v[2]=(short)f2b(q0.z); v[3]=(short)f2b(q0.w);
  v[4]=(short)f2b(q1.x); v[5]=(short)f2b(q1.y); v[6]=(short)f2b(q1.z); v[7]=(short)f2b(q1.w);
  *(short8*)(h16 + (size_t)i * 8) = v;
}

// ---- weight panel staging via global_load_lds DMA (linear copy; panels pre-swizzled) ----
// dest: wave-uniform base + lane*16 (HW); source per-lane linear -> byte-identical to R8 image
#define WDMA(pn) { \
  const char* gs_ = wsb + (size_t)(pn) * 16384 + wv * 1024 + lane * 16; \
  char* ld_ = &Wbuf[(pn) & 1][wv * 1024]; \
  __builtin_amdgcn_global_load_lds((gas_void*)gs_, (las_void*)ld_, 16, 0, 0); \
  __builtin_amdgcn_global_load_lds((gas_void*)(gs_ + 8192), (las_void*)(ld_ + 8192), 16, 0, 0); }

// ---- gather staging (reg-staged; swizzled dest) ----
#define LOADC(c) { const int c_ = (c); \
  int nd_ = ((c_>>1)==0)?idx4.x:((c_>>1)==1)?idx4.y:((c_>>1)==2)?idx4.z:idx4.w; \
  const size_t o_ = (size_t)nd_ * 128 + (c_ & 1) * 64 + sq * 16; \
  if (H16){ rgA = *(const short8*)(h16 + o_); rgB = *(const short8*)(h16 + o_ + 8); } \
  else { float4 qa_=*(const float4*)(h+o_), qb_=*(const float4*)(h+o_+4); \
         float4 qc_=*(const float4*)(h+o_+8), qd_=*(const float4*)(h+o_+12); \
    rgA[0]=(short)f2b(qa_.x); rgA[1]=(short)f2b(qa_.y); rgA[2]=(short)f2b(qa_.z); rgA[3]=(short)f2b(qa_.w); \
    rgA[4]=(short)f2b(qb_.x); rgA[5]=(short)f2b(qb_.y); rgA[6]=(short)f2b(qb_.z); rgA[7]=(short)f2b(qb_.w); \
    rgB[0]=(short)f2b(qc_.x); rgB[1]=(short)f2b(qc_.y); rgB[2]=(short)f2b(qc_.z); rgB[3]=(short)f2b(qc_.w); \
    rgB[4]=(short)f2b(qd_.x); rgB[5]=(short)f2b(qd_.y); rgB[6]=(short)f2b(qd_.z); rgB[7]=(short)f2b(qd_.w); } }
#define STOREC(c) { char* b_ = Zb + (((c) & 1) << 14) + srow * 128; const int sw_ = (srow & 7) << 4; \
  *(short8*)(b_ + ((sq * 32) ^ sw_))      = rgA; \
  *(short8*)(b_ + ((sq * 32 + 16) ^ sw_)) = rgB; }

// ---- fragment loads / MFMA cluster (addresses reduced to lane-constant + literal) ----
#define LDA4(D_, SRC_, RS_, KB_) { const int ao_ = ((KB_) + lg * 16) ^ aswz; \
  _Pragma("unroll") for (int af_ = 0; af_ < 4; ++af_){ \
    const int r_ = wm * 64 + af_ * 16 + lr; \
    D_[af_] = *(const short8*)((SRC_) + r_ * (RS_) + ao_); } }

#define GEMMF(bf_, A_) { \
  const char* wb_ = Wbuf[bf_] + wbase; \
  short8 w0_ = *(const short8*)(wb_); \
  short8 w1_ = *(const short8*)(wb_ + 1024); \
  short8 w2_ = *(const short8*)(wb_ + 2048); \
  short8 w3_ = *(const short8*)(wb_ + 3072); \
  __builtin_amdgcn_s_setprio(1); \
  _Pragma("unroll") for (int af_ = 0; af_ < 4; ++af_){ \
    acc[0][af_] = __builtin_amdgcn_mfma_f32_16x16x32_bf16(w0_, A_[af_], acc[0][af_], 0, 0, 0); \
    acc[1][af_] = __builtin_amdgcn_mfma_f32_16x16x32_bf16(w1_, A_[af_], acc[1][af_], 0, 0, 0); \
    acc[2][af_] = __builtin_amdgcn_mfma_f32_16x16x32_bf16(w2_, A_[af_], acc[2][af_], 0, 0, 0); \
    acc[3][af_] = __builtin_amdgcn_mfma_f32_16x16x32_bf16(w3_, A_[af_], acc[3][af_], 0, 0, 0); } \
  __builtin_amdgcn_s_setprio(0); }

#define ZERO_ACC() { _Pragma("unroll") for (int i_ = 0; i_ < 4; ++i_) \
  _Pragma("unroll") for (int j_ = 0; j_ < 4; ++j_) acc[i_][j_] = (f32x4){0.f,0.f,0.f,0.f}; }

template<bool H16>
__global__ __launch_bounds__(512) void torsion_kernel(
    const float* __restrict__ h, const u16* __restrict__ h16,
    const int* __restrict__ idxs, const float* __restrict__ sb,
    const float* __restrict__ c_rb, const float* __restrict__ c_b1, const float* __restrict__ c_b2,
    const float* __restrict__ t_rb, const float* __restrict__ t_b1, const float* __restrict__ t_b2,
    const u16* __restrict__ ws, float* __restrict__ out, int NT)
{
  __shared__ __attribute__((aligned(16))) char Xb[65536];      // [128][256] bf16 swizzled
  __shared__ __attribute__((aligned(16))) char Zb[65536];      // gather 2x16KB, then Y/V
  __shared__ __attribute__((aligned(16))) char Wbuf[2][16384]; // weight panel dbuf (DMA target)

  const int tid = threadIdx.x, blk = blockIdx.x;
  const int lane = tid & 63, lr = lane & 15, lg = lane >> 4;
  const int wv = tid >> 6, wm = wv & 1, wn = wv >> 1;
  const char* wsb = (const char*)ws;

  const int srow = tid >> 2, sq = tid & 3;
  const int sgrow = blk * 128 + srow;
  int4 idx4 = (sgrow < NT) ? ((const int4*)idxs)[sgrow] : (int4){0, 0, 0, 0};
  short8 rgA, rgB;                 // gather staging regs

  // lane-constant address components
  const int aswz  = (lr & 7) << 4;                               // A-frag XOR
  const int wbase = (wn * 64 + lr) * 64 + ((lg * 16) ^ (((lr >> 1) & 3) << 4)); // W-frag base

  f32x4 acc[4][4];
  ZERO_ACC();

  // ---- prologue: DMA panel 0, stage gather chunk 0 ----
  WDMA(0);
  LOADC(0); STOREC(0);
  __syncthreads();

  // ================ stage A: x = elu(concat(h[idx]) @ sw.T + sb), phases 0..15 ================
  short8 aS0[4], aS1[4];
  #pragma unroll
  for (int p = 0; p < 16; ++p){
    if ((p & 1) && p < 15) STOREC((p >> 1) + 1);
    WDMA(p + 1);
    if (!(p & 1) && p < 14) LOADC((p >> 1) + 1);
    const char* cb = Zb + (((p >> 1) & 1) << 14);
    if (p & 1){
      GEMMF(p & 1, aS1);                       // A-frags prefetched last phase
    } else {
      LDA4(aS0, cb, 128, 0);
      GEMMF(p & 1, aS0);
      LDA4(aS1, cb, 128, 64);                  // prefetch next (same chunk)
    }
    if (p == 15){
      #pragma unroll
      for (int wf = 0; wf < 4; ++wf){
        const int col0 = wn * 64 + wf * 16 + lg * 4;
        const float4 bb = *(const float4*)(sb + col0);
        #pragma unroll
        for (int af = 0; af < 4; ++af){
          const int row = wm * 64 + af * 16 + lr;
          u32x2 pk = { packbf(elu1(acc[wf][af][0] + bb.x), elu1(acc[wf][af][1] + bb.y)),
                       packbf(elu1(acc[wf][af][2] + bb.z), elu1(acc[wf][af][3] + bb.w)) };
          *(u32x2*)(Xb + row * 512 + ((col0 * 2) ^ ((row & 7) << 4))) = pk;
        }
      }
    }
    __syncthreads();
  }

  // ================ heads: c (score, panels 16..32) then t (coeffs, 33..49) ================
  f32x4 scC = (f32x4){0,0,0,0}, scT = (f32x4){0,0,0,0};
  short8 aP0[4], aP1[4];
  #pragma unroll
  for (int hd = 0; hd < 2; ++hd){
    const int pb = 16 + hd * 17;
    const float* RB = hd ? t_rb : c_rb;
    const float* B1 = hd ? t_b1 : c_b1;
    const float* B2 = hd ? t_b2 : c_b2;

    // ---- y = x + elu(x @ rw.T + rb)  (reads Xb; kk==7 epilogue writes Zb) ----
    ZERO_ACC();
    LDA4(aP0, Xb, 512, 0);
    #pragma unroll
    for (int kk = 0; kk < 8; ++kk){
      const int p = pb + kk;
      WDMA(p + 1);
      if (kk & 1){ GEMMF(p & 1, aP1); } else { GEMMF(p & 1, aP0); }
      if (kk < 7){
        if (kk & 1){ LDA4(aP0, Xb, 512, (kk + 1) * 64); }
        else       { LDA4(aP1, Xb, 512, (kk + 1) * 64); }
      } else {
        #pragma unroll
        for (int wf = 0; wf < 4; ++wf){
          const int col0 = wn * 64 + wf * 16 + lg * 4;
          const float4 bb = *(const float4*)(RB + col0);
          #pragma unroll
          for (int af = 0; af < 4; ++af){
            const int row = wm * 64 + af * 16 + lr;
            const int boff = (col0 * 2) ^ ((row & 7) << 4);
            u32x2 xv = *(const u32x2*)(Xb + row * 512 + boff);
            float y0 = b2f((u16)(xv[0] & 0xffff)) + elu1(acc[wf][af][0] + bb.x);
            float y1 = b2f((u16)(xv[0] >> 16))    + elu1(acc[wf][af][1] + bb.y);
            float y2 = b2f((u16)(xv[1] & 0xffff)) + elu1(acc[wf][af][2] + bb.z);
            float y3 = b2f((u16)(xv[1] >> 16))    + elu1(acc[wf][af][3] + bb.w);
            u32x2 pk = { packbf(y0, y1), packbf(y2, y3) };
            *(u32x2*)(Zb + row * 512 + boff) = pk;
          }
        }
      }
      __syncthreads();
    }

    // ---- v = elu(y @ w1.T + b1)  (reads Zb(Y); kk==7: drain reads, overwrite Zb with V) ----
    ZERO_ACC();
    LDA4(aP0, Zb, 512, 0);
    #pragma unroll
    for (int kk = 0; kk < 8; ++kk){
      const int p = pb + 8 + kk;
      WDMA(p + 1);
      if (kk & 1){ GEMMF(p & 1, aP1); } else { GEMMF(p & 1, aP0); }
      if (kk < 7){
        if (kk & 1){ LDA4(aP0, Zb, 512, (kk + 1) * 64); }
        else       { LDA4(aP1, Zb, 512, (kk + 1) * 64); }
        __syncthreads();
      } else {
        __syncthreads();               // all Y reads complete before V overwrites Zb
        #pragma unroll
        for (int wf = 0; wf < 4; ++wf){
          const int col0 = wn * 64 + wf * 16 + lg * 4;
          const float4 bb = *(const float4*)(B1 + col0);
          #pragma unroll
          for (int af = 0; af < 4; ++af){
            const int row = wm * 64 + af * 16 + lr;
            u32x2 pk = { packbf(elu1(acc[wf][af][0] + bb.x), elu1(acc[wf][af][1] + bb.y)),
                         packbf(elu1(acc[wf][af][2] + bb.z), elu1(acc[wf][af][3] + bb.w)) };
            *(u32x2*)(Zb + row * 512 + ((col0 * 2) ^ ((row & 7) << 4))) = pk;
          }
        }
        __syncthreads();
      }
    }

    // ---- out16 = v @ w2p.T  (wave wv owns rows wv*16..+15) ----
    {
      const int p2 = pb + 16;
      if (p2 + 1 < NPANEL) WDMA(p2 + 1);
      f32x4 a1 = (f32x4){0, 0, 0, 0};
      const int vr = wv * 16 + lr;
      __builtin_amdgcn_s_setprio(1);
      #pragma unroll
      for (int kt = 0; kt < 8; ++kt){
        short8 aw = *(const short8*)(Wbuf[p2 & 1] + lr * 512 + ((kt * 64 + lg * 16) ^ ((lr & 7) << 4)));
        short8 bv = *(const short8*)(Zb + vr * 512 + ((kt * 64 + lg * 16) ^ ((vr & 7) << 4)));
        a1 = __builtin_amdgcn_mfma_f32_16x16x32_bf16(aw, bv, a1, 0, 0, 0);
      }
      __builtin_amdgcn_s_setprio(0);
      #pragma unroll
      for (int r = 0; r < 4; ++r){
        const int nn = lg * 4 + r;
        a1[r] += (nn < NPER) ? B2[nn] : 0.f;
      }
      if (hd == 0) scC = a1; else scT = a1;
      __syncthreads();
    }
  }

  // ---- epilogue: score & coeff for row (wv*16+lr) both live in this lane ----
  const int grow = blk * 128 + wv * 16 + lr;
  if (grow < NT){
    #pragma unroll
    for (int r = 0; r < 4; ++r){
      const int nn = lg * 4 + r;
      if (nn < NPER){
        const float s = scC[r], c = scT[r];
        out[(size_t)grow * 6 + nn] = s;
        out[(size_t)NT * 6 + (size_t)grow * 6 + nn] = c * 1e-3f * (1.f / (1.f + __expf(-s)));
      }
    }
  }
}

extern "C" void kernel_launch(void* const* d_in, const int* in_sizes, int n_in,
                              void* d_out, int out_size, void* d_ws, size_t ws_size,
                              hipStream_t stream){
  const float* h    = (const float*)d_in[0];
  const int*   idxs = (const int*)d_in[1];
  const float* sw   = (const float*)d_in[2];
  const float* sb   = (const float*)d_in[3];
  const float* trw  = (const float*)d_in[4];
  const float* trb  = (const float*)d_in[5];
  const float* tw1  = (const float*)d_in[6];
  const float* tb1  = (const float*)d_in[7];
  const float* tw2  = (const float*)d_in[8];
  const float* tb2  = (const float*)d_in[9];
  const float* crw  = (const float*)d_in[10];
  const float* crb  = (const float*)d_in[11];
  const float* cw1  = (const float*)d_in[12];
  const float* cb1  = (const float*)d_in[13];
  const float* cw2  = (const float*)d_in[14];
  const float* cb2  = (const float*)d_in[15];
  u16* ws    = (u16*)d_ws;
  float* out = (float*)d_out;
  const int NT = in_sizes[1] / 4;
  const int nh = in_sizes[0];
  const bool useH16 = ws_size >= (size_t)(WS_WELE + nh) * 2;

  hipLaunchKernelGGL(convert_weights, dim3((WS_WELE + 255) / 256), dim3(256), 0, stream,
                     sw, crw, cw1, cw2, trw, tw1, tw2, ws);
  u16* h16 = ws + WS_WELE;
  const int nblk = (NT + 127) / 128;
  if (useH16){
    const int n8 = nh / 8;
    hipLaunchKernelGGL(convert_h, dim3((n8 + 255) / 256), dim3(256), 0, stream, h, h16, n8);
    torsion_kernel<true><<<dim3(nblk), dim3(512), 0, stream>>>(
        h, h16, idxs, sb, crb, cb1, cb2, trb, tb1, tb2, ws, out, NT);
  } else {
    torsion_kernel<false><<<dim3(nblk), dim3(512), 0, stream>>>(
        h, h16, idxs, sb, crb, cb1, cb2, trb, tb1, tb2, ws, out, NT);
  }
}

// Round 10
// 558.589 us; speedup vs baseline: 1.2560x; 1.2560x over previous
//
#include <hip/hip_runtime.h>
#include <stdint.h>

typedef __attribute__((ext_vector_type(8))) short short8;
typedef __attribute__((ext_vector_type(4))) float f32x4;
typedef __attribute__((ext_vector_type(2))) unsigned int u32x2;
typedef unsigned short u16;
typedef unsigned int u32;

#define NPER 6
// frag-major weight regions (bf16 element offsets). Each frag = 512 elems = 1KB,
// laid out lane-major: frag[lane][j] = W[n(frag,lane)][k(frag,lane,j)].
#define SA_F   0         // 256 frags: ks 0..15 x fid 0..15   (shared 512-k layer)
#define CRW_F  131072    // 128 frags: ks 0..7  x fid 0..15
#define CW1_F  196608
#define CW2_F  262144    // 8 frags (n=lr rows 0..15, rows>=6 zero)
#define TRW_F  266240
#define TW1_F  331776
#define TW2_F  397312
#define WS_WELE 401408   // h16 follows

__device__ inline u16 f2b(float f){                 // f32 -> bf16 (RNE)
  u32 u = __builtin_bit_cast(u32, f);
  u = u + 0x7FFFu + ((u >> 16) & 1u);
  return (u16)(u >> 16);
}
__device__ inline float b2f(u16 v){ return __builtin_bit_cast(float, ((u32)v) << 16); }
__device__ inline float elu1(float x){ return x > 0.f ? x : (__expf(x) - 1.f); }
__device__ inline u32 packbf(float a, float b){ return (u32)f2b(a) | ((u32)f2b(b) << 16); }

// ---- frag-major weight conversion ----
__global__ __launch_bounds__(256) void convert_weights(
    const float* __restrict__ sw, const float* __restrict__ crw, const float* __restrict__ cw1,
    const float* __restrict__ cw2, const float* __restrict__ trw, const float* __restrict__ tw1,
    const float* __restrict__ tw2, u16* __restrict__ ws){
  int i = blockIdx.x * 256 + threadIdx.x;
  if (i >= WS_WELE) return;
  int e = i & 511;
  int lane = e >> 3, j = e & 7, lr = lane & 15, lg = lane >> 4;
  float v;
  if (i < CRW_F){        int fs = i >> 9;              int n = (fs & 15) * 16 + lr, k = (fs >> 4) * 32 + lg * 8 + j; v = sw[n * 512 + k]; }
  else if (i < CW1_F){   int fs = (i - CRW_F) >> 9;    int n = (fs & 15) * 16 + lr, k = (fs >> 4) * 32 + lg * 8 + j; v = crw[n * 256 + k]; }
  else if (i < CW2_F){   int fs = (i - CW1_F) >> 9;    int n = (fs & 15) * 16 + lr, k = (fs >> 4) * 32 + lg * 8 + j; v = cw1[n * 256 + k]; }
  else if (i < TRW_F){   int fs = (i - CW2_F) >> 9;    int k = fs * 32 + lg * 8 + j; v = (lr < NPER) ? cw2[lr * 256 + k] : 0.f; }
  else if (i < TW1_F){   int fs = (i - TRW_F) >> 9;    int n = (fs & 15) * 16 + lr, k = (fs >> 4) * 32 + lg * 8 + j; v = trw[n * 256 + k]; }
  else if (i < TW2_F){   int fs = (i - TW1_F) >> 9;    int n = (fs & 15) * 16 + lr, k = (fs >> 4) * 32 + lg * 8 + j; v = tw1[n * 256 + k]; }
  else {                 int fs = (i - TW2_F) >> 9;    int k = fs * 32 + lg * 8 + j; v = (lr < NPER) ? tw2[lr * 256 + k] : 0.f; }
  ws[i] = f2b(v);
}

__global__ __launch_bounds__(256) void convert_h(
    const float* __restrict__ h, u16* __restrict__ h16, int n8){
  int i = blockIdx.x * 256 + threadIdx.x;
  if (i >= n8) return;
  const float4* src = (const float4*)(h + (size_t)i * 8);
  float4 q0 = src[0], q1 = src[1];
  short8 v;
  v[0]=(short)f2b(q0.x); v[1]=(short)f2b(q0.y); v[2]=(short)f2b(q0.z); v[3]=(short)f2b(q0.w);
  v[4]=(short)f2b(q1.x); v[5]=(short)f2b(q1.y); v[6]=(short)f2b(q1.z); v[7]=(short)f2b(q1.w);
  *(short8*)(h16 + (size_t)i * 8) = v;
}

// ---- in-kernel macros ----
// W frag: coalesced per-lane global load (lane-major 1KB frag)
#define WF(D_, BASE_, FS_) { D_ = ((const short8*)(ws + (BASE_) + (size_t)(FS_) * 512))[lane]; }
#define WF4(D_, BASE_, KS_) { WF(D_##0, BASE_, (KS_)*16 + fq + 0); WF(D_##1, BASE_, (KS_)*16 + fq + 1); \
                              WF(D_##2, BASE_, (KS_)*16 + fq + 2); WF(D_##3, BASE_, (KS_)*16 + fq + 3); }
// A frags from swizzled LDS
#define LDA4(D_, SRC_, RS_, KB_) { const int ao_ = ((KB_) + lg * 16) ^ aswz; \
  _Pragma("unroll") for (int af_ = 0; af_ < 4; ++af_){ \
    const int r_ = wm * 64 + af_ * 16 + lr; \
    D_[af_] = *(const short8*)((SRC_) + r_ * (RS_) + ao_); } }
// 16 MFMA cluster
#define GEMM16(W_, A_) { __builtin_amdgcn_s_setprio(1); \
  _Pragma("unroll") for (int af_ = 0; af_ < 4; ++af_){ \
    acc[0][af_] = __builtin_amdgcn_mfma_f32_16x16x32_bf16(W_##0, A_[af_], acc[0][af_], 0, 0, 0); \
    acc[1][af_] = __builtin_amdgcn_mfma_f32_16x16x32_bf16(W_##1, A_[af_], acc[1][af_], 0, 0, 0); \
    acc[2][af_] = __builtin_amdgcn_mfma_f32_16x16x32_bf16(W_##2, A_[af_], acc[2][af_], 0, 0, 0); \
    acc[3][af_] = __builtin_amdgcn_mfma_f32_16x16x32_bf16(W_##3, A_[af_], acc[3][af_], 0, 0, 0); } \
  __builtin_amdgcn_s_setprio(0); }
#define ZERO_ACC() { _Pragma("unroll") for (int i_ = 0; i_ < 4; ++i_) \
  _Pragma("unroll") for (int j_ = 0; j_ < 4; ++j_) acc[i_][j_] = (f32x4){0.f,0.f,0.f,0.f}; }
// lgkm-only barrier: global loads stay in flight (R8-verified)
#define BAR() { asm volatile("s_waitcnt lgkmcnt(0)" ::: "memory"); \
  __builtin_amdgcn_sched_barrier(0); \
  __builtin_amdgcn_s_barrier(); \
  __builtin_amdgcn_sched_barrier(0); }
// gather staging (BM=128): thread stages row srow, 32B at granule pair sq
#define LOADC(c) { const int c_ = (c); \
  int nd_ = ((c_>>1)==0)?idx4.x:((c_>>1)==1)?idx4.y:((c_>>1)==2)?idx4.z:idx4.w; \
  const size_t o_ = (size_t)nd_ * 128 + (c_ & 1) * 64 + sq * 16; \
  if (H16){ rgA = *(const short8*)(h16 + o_); rgB = *(const short8*)(h16 + o_ + 8); } \
  else { float4 qa_=*(const float4*)(h+o_), qb_=*(const float4*)(h+o_+4); \
         float4 qc_=*(const float4*)(h+o_+8), qd_=*(const float4*)(h+o_+12); \
    rgA[0]=(short)f2b(qa_.x); rgA[1]=(short)f2b(qa_.y); rgA[2]=(short)f2b(qa_.z); rgA[3]=(short)f2b(qa_.w); \
    rgA[4]=(short)f2b(qb_.x); rgA[5]=(short)f2b(qb_.y); rgA[6]=(short)f2b(qb_.z); rgA[7]=(short)f2b(qb_.w); \
    rgB[0]=(short)f2b(qc_.x); rgB[1]=(short)f2b(qc_.y); rgB[2]=(short)f2b(qc_.z); rgB[3]=(short)f2b(qc_.w); \
    rgB[4]=(short)f2b(qd_.x); rgB[5]=(short)f2b(qd_.y); rgB[6]=(short)f2b(qd_.z); rgB[7]=(short)f2b(qd_.w); } }
#define STOREC(c) { char* b_ = Zb + (((c) & 1) << 14) + srow * 128; const int sw_ = (srow & 7) << 4; \
  *(short8*)(b_ + ((sq * 32) ^ sw_))      = rgA; \
  *(short8*)(b_ + ((sq * 32 + 16) ^ sw_)) = rgB; }
// one 256-k layer, 8 k-steps, W/A 1-deep prefetch, no internal barriers
#define LAYER256(WBASE_, AB_) { \
  WF4(wfA, WBASE_, 0); \
  LDA4(afA, AB_, 512, 0); \
  _Pragma("unroll") for (int ks_ = 0; ks_ < 8; ++ks_){ \
    if (ks_ & 1){ \
      if (ks_ < 7){ WF4(wfA, WBASE_, ks_ + 1); LDA4(afA, AB_, 512, (ks_ + 1) * 64); } \
      GEMM16(wfB, afB); \
    } else { \
      WF4(wfB, WBASE_, ks_ + 1); LDA4(afB, AB_, 512, (ks_ + 1) * 64); \
      GEMM16(wfA, afA); \
    } } }

template<bool H16>
__global__ __launch_bounds__(512) void torsion_kernel(
    const float* __restrict__ h, const u16* __restrict__ h16,
    const int* __restrict__ idxs, const float* __restrict__ sb,
    const float* __restrict__ c_rb, const float* __restrict__ c_b1, const float* __restrict__ c_b2,
    const float* __restrict__ t_rb, const float* __restrict__ t_b1, const float* __restrict__ t_b2,
    const u16* __restrict__ ws, float* __restrict__ out, int NT)
{
  __shared__ __attribute__((aligned(16))) char Xb[65536];   // [128][256] bf16 swizzled
  __shared__ __attribute__((aligned(16))) char Zb[65536];   // gather dbuf 2x16KB, then Y/V

  const int tid = threadIdx.x, blk = blockIdx.x;
  const int lane = tid & 63, lr = lane & 15, lg = lane >> 4;
  const int wv = tid >> 6, wm = wv & 1, wn = wv >> 1;
  const int fq = wn * 4;                        // this wave's frag quarter
  const int aswz = (lr & 7) << 4;

  const int srow = tid >> 2, sq = tid & 3;
  const int sgrow = blk * 128 + srow;
  int4 idx4 = (sgrow < NT) ? ((const int4*)idxs)[sgrow] : (int4){0, 0, 0, 0};
  short8 rgA, rgB;
  short8 wfA0, wfA1, wfA2, wfA3, wfB0, wfB1, wfB2, wfB3;
  short8 afA[4], afB[4];

  f32x4 acc[4][4];
  ZERO_ACC();

  // ---- prologue: gather chunk 0 staged; first W frags in flight ----
  LOADC(0); STOREC(0);
  WF4(wfA, SA_F, 0);
  BAR();
  LDA4(afA, Zb, 128, 0);

  // ================ stage A: x = elu(concat(h[idx]) @ sw.T + sb); 8 chunks, 1 bar each ================
  #pragma unroll
  for (int c = 0; c < 8; ++c){
    const char* cb = Zb + ((c & 1) << 14);
    if (c < 7) LOADC(c + 1);
    WF4(wfB, SA_F, 2 * c + 1);
    LDA4(afB, cb, 128, 64);
    GEMM16(wfA, afA);
    if (c < 7) WF4(wfA, SA_F, 2 * c + 2);
    GEMM16(wfB, afB);
    if (c < 7) STOREC(c + 1);
    if (c == 7){
      // X epilogue: elu + bias -> Xb (swizzled bf16)
      #pragma unroll
      for (int wf = 0; wf < 4; ++wf){
        const int col0 = wn * 64 + wf * 16 + lg * 4;
        const float4 bb = *(const float4*)(sb + col0);
        #pragma unroll
        for (int af = 0; af < 4; ++af){
          const int row = wm * 64 + af * 16 + lr;
          u32x2 pk = { packbf(elu1(acc[wf][af][0] + bb.x), elu1(acc[wf][af][1] + bb.y)),
                       packbf(elu1(acc[wf][af][2] + bb.z), elu1(acc[wf][af][3] + bb.w)) };
          *(u32x2*)(Xb + row * 512 + ((col0 * 2) ^ ((row & 7) << 4))) = pk;
        }
      }
    }
    BAR();
    if (c < 7) LDA4(afA, Zb + (((c + 1) & 1) << 14), 128, 0);
  }

  // ================ heads: c (score) then t (coeffs) ================
  f32x4 scC = (f32x4){0,0,0,0}, scT = (f32x4){0,0,0,0};
  #pragma unroll
  for (int hd = 0; hd < 2; ++hd){
    const int RWF = hd ? TRW_F : CRW_F;
    const int W1F = hd ? TW1_F : CW1_F;
    const int W2F = hd ? TW2_F : CW2_F;
    const float* RB = hd ? t_rb : c_rb;
    const float* B1 = hd ? t_b1 : c_b1;
    const float* B2 = hd ? t_b2 : c_b2;

    // ---- y = x + elu(x @ rw.T + rb): layer, then Y epilogue -> Zb ----
    ZERO_ACC();
    LAYER256(RWF, Xb);
    #pragma unroll
    for (int wf = 0; wf < 4; ++wf){
      const int col0 = wn * 64 + wf * 16 + lg * 4;
      const float4 bb = *(const float4*)(RB + col0);
      #pragma unroll
      for (int af = 0; af < 4; ++af){
        const int row = wm * 64 + af * 16 + lr;
        const int boff = (col0 * 2) ^ ((row & 7) << 4);
        u32x2 xv = *(const u32x2*)(Xb + row * 512 + boff);
        float y0 = b2f((u16)(xv[0] & 0xffff)) + elu1(acc[wf][af][0] + bb.x);
        float y1 = b2f((u16)(xv[0] >> 16))    + elu1(acc[wf][af][1] + bb.y);
        float y2 = b2f((u16)(xv[1] & 0xffff)) + elu1(acc[wf][af][2] + bb.z);
        float y3 = b2f((u16)(xv[1] >> 16))    + elu1(acc[wf][af][3] + bb.w);
        u32x2 pk = { packbf(y0, y1), packbf(y2, y3) };
        *(u32x2*)(Zb + row * 512 + boff) = pk;
      }
    }
    BAR();                                  // Y visible

    // ---- v = elu(y @ w1.T + b1): layer, drain-bar, V epilogue -> Zb ----
    ZERO_ACC();
    LAYER256(W1F, Zb);
    BAR();                                  // all Y reads done before overwrite
    #pragma unroll
    for (int wf = 0; wf < 4; ++wf){
      const int col0 = wn * 64 + wf * 16 + lg * 4;
      const float4 bb = *(const float4*)(B1 + col0);
      #pragma unroll
      for (int af = 0; af < 4; ++af){
        const int row = wm * 64 + af * 16 + lr;
        u32x2 pk = { packbf(elu1(acc[wf][af][0] + bb.x), elu1(acc[wf][af][1] + bb.y)),
                     packbf(elu1(acc[wf][af][2] + bb.z), elu1(acc[wf][af][3] + bb.w)) };
        *(u32x2*)(Zb + row * 512 + ((col0 * 2) ^ ((row & 7) << 4))) = pk;
      }
    }
    BAR();                                  // V visible

    // ---- out16 = v @ w2p.T: wave wv owns rows wv*16..+15 ----
    {
      f32x4 a1 = (f32x4){0, 0, 0, 0};
      const int vr = wv * 16 + lr;
      const int vswz = (vr & 7) << 4;
      __builtin_amdgcn_s_setprio(1);
      #pragma unroll
      for (int kt = 0; kt < 8; ++kt){
        short8 aw; WF(aw, W2F, kt);
        short8 bv = *(const short8*)(Zb + vr * 512 + ((kt * 64 + lg * 16) ^ vswz));
        a1 = __builtin_amdgcn_mfma_f32_16x16x32_bf16(aw, bv, a1, 0, 0, 0);
      }
      __builtin_amdgcn_s_setprio(0);
      #pragma unroll
      for (int r = 0; r < 4; ++r){
        const int nn = lg * 4 + r;
        a1[r] += (nn < NPER) ? B2[nn] : 0.f;
      }
      if (hd == 0) scC = a1; else scT = a1;
      BAR();                                // w2's V reads done before head t's Y overwrites
    }
  }

  // ---- epilogue: score & coeff for row (wv*16+lr) live in this lane ----
  const int grow = blk * 128 + wv * 16 + lr;
  if (grow < NT){
    #pragma unroll
    for (int r = 0; r < 4; ++r){
      const int nn = lg * 4 + r;
      if (nn < NPER){
        const float s = scC[r], c = scT[r];
        out[(size_t)grow * 6 + nn] = s;
        out[(size_t)NT * 6 + (size_t)grow * 6 + nn] = c * 1e-3f * (1.f / (1.f + __expf(-s)));
      }
    }
  }
}

extern "C" void kernel_launch(void* const* d_in, const int* in_sizes, int n_in,
                              void* d_out, int out_size, void* d_ws, size_t ws_size,
                              hipStream_t stream){
  const float* h    = (const float*)d_in[0];
  const int*   idxs = (const int*)d_in[1];
  const float* sw   = (const float*)d_in[2];
  const float* sb   = (const float*)d_in[3];
  const float* trw  = (const float*)d_in[4];
  const float* trb  = (const float*)d_in[5];
  const float* tw1  = (const float*)d_in[6];
  const float* tb1  = (const float*)d_in[7];
  const float* tw2  = (const float*)d_in[8];
  const float* tb2  = (const float*)d_in[9];
  const float* crw  = (const float*)d_in[10];
  const float* crb  = (const float*)d_in[11];
  const float* cw1  = (const float*)d_in[12];
  const float* cb1  = (const float*)d_in[13];
  const float* cw2  = (const float*)d_in[14];
  const float* cb2  = (const float*)d_in[15];
  u16* ws    = (u16*)d_ws;
  float* out = (float*)d_out;
  const int NT = in_sizes[1] / 4;
  const int nh = in_sizes[0];
  const bool useH16 = ws_size >= (size_t)(WS_WELE + nh) * 2;

  hipLaunchKernelGGL(convert_weights, dim3((WS_WELE + 255) / 256), dim3(256), 0, stream,
                     sw, crw, cw1, cw2, trw, tw1, tw2, ws);
  u16* h16 = ws + WS_WELE;
  const int nblk = (NT + 127) / 128;
  if (useH16){
    const int n8 = nh / 8;
    hipLaunchKernelGGL(convert_h, dim3((n8 + 255) / 256), dim3(256), 0, stream, h, h16, n8);
    torsion_kernel<true><<<dim3(nblk), dim3(512), 0, stream>>>(
        h, h16, idxs, sb, crb, cb1, cb2, trb, tb1, tb2, ws, out, NT);
  } else {
    torsion_kernel<false><<<dim3(nblk), dim3(512), 0, stream>>>(
        h, h16, idxs, sb, crb, cb1, cb2, trb, tb1, tb2, ws, out, NT);
  }
}

// Round 11
// 513.951 us; speedup vs baseline: 1.3651x; 1.0869x over previous
//
#include <hip/hip_runtime.h>
#include <stdint.h>

typedef __attribute__((ext_vector_type(8))) short short8;
typedef __attribute__((ext_vector_type(4))) float f32x4;
typedef __attribute__((ext_vector_type(2))) unsigned int u32x2;
typedef unsigned short u16;
typedef unsigned int u32;

#define NPER 6
// frag-major weight regions (bf16 element offsets). Each frag = 512 elems = 1KB,
// lane-major: frag[lane][j] = W[n(frag,lane)][k(frag,lane,j)].   (identical to R10)
#define SA_F   0
#define CRW_F  131072
#define CW1_F  196608
#define CW2_F  262144
#define TRW_F  266240
#define TW1_F  331776
#define TW2_F  397312
#define WS_WELE 401408   // h16 follows

__device__ inline u16 f2b(float f){                 // f32 -> bf16 (RNE)
  u32 u = __builtin_bit_cast(u32, f);
  u = u + 0x7FFFu + ((u >> 16) & 1u);
  return (u16)(u >> 16);
}
__device__ inline float b2f(u16 v){ return __builtin_bit_cast(float, ((u32)v) << 16); }
__device__ inline float elu1(float x){ return x > 0.f ? x : (__expf(x) - 1.f); }
__device__ inline u32 packbf(float a, float b){ return (u32)f2b(a) | ((u32)f2b(b) << 16); }

// ---- frag-major weight conversion (identical to R10) ----
__global__ __launch_bounds__(256) void convert_weights(
    const float* __restrict__ sw, const float* __restrict__ crw, const float* __restrict__ cw1,
    const float* __restrict__ cw2, const float* __restrict__ trw, const float* __restrict__ tw1,
    const float* __restrict__ tw2, u16* __restrict__ ws){
  int i = blockIdx.x * 256 + threadIdx.x;
  if (i >= WS_WELE) return;
  int e = i & 511;
  int lane = e >> 3, j = e & 7, lr = lane & 15, lg = lane >> 4;
  float v;
  if (i < CRW_F){        int fs = i >> 9;              int n = (fs & 15) * 16 + lr, k = (fs >> 4) * 32 + lg * 8 + j; v = sw[n * 512 + k]; }
  else if (i < CW1_F){   int fs = (i - CRW_F) >> 9;    int n = (fs & 15) * 16 + lr, k = (fs >> 4) * 32 + lg * 8 + j; v = crw[n * 256 + k]; }
  else if (i < CW2_F){   int fs = (i - CW1_F) >> 9;    int n = (fs & 15) * 16 + lr, k = (fs >> 4) * 32 + lg * 8 + j; v = cw1[n * 256 + k]; }
  else if (i < TRW_F){   int fs = (i - CW2_F) >> 9;    int k = fs * 32 + lg * 8 + j; v = (lr < NPER) ? cw2[lr * 256 + k] : 0.f; }
  else if (i < TW1_F){   int fs = (i - TRW_F) >> 9;    int n = (fs & 15) * 16 + lr, k = (fs >> 4) * 32 + lg * 8 + j; v = trw[n * 256 + k]; }
  else if (i < TW2_F){   int fs = (i - TW1_F) >> 9;    int n = (fs & 15) * 16 + lr, k = (fs >> 4) * 32 + lg * 8 + j; v = tw1[n * 256 + k]; }
  else {                 int fs = (i - TW2_F) >> 9;    int k = fs * 32 + lg * 8 + j; v = (lr < NPER) ? tw2[lr * 256 + k] : 0.f; }
  ws[i] = f2b(v);
}

__global__ __launch_bounds__(256) void convert_h(
    const float* __restrict__ h, u16* __restrict__ h16, int n8){
  int i = blockIdx.x * 256 + threadIdx.x;
  if (i >= n8) return;
  const float4* src = (const float4*)(h + (size_t)i * 8);
  float4 q0 = src[0], q1 = src[1];
  short8 v;
  v[0]=(short)f2b(q0.x); v[1]=(short)f2b(q0.y); v[2]=(short)f2b(q0.z); v[3]=(short)f2b(q0.w);
  v[4]=(short)f2b(q1.x); v[5]=(short)f2b(q1.y); v[6]=(short)f2b(q1.z); v[7]=(short)f2b(q1.w);
  *(short8*)(h16 + (size_t)i * 8) = v;
}

// ---- in-kernel macros (R10, wm removed: rows 0..63) ----
#define WF(D_, BASE_, FS_) { D_ = ((const short8*)(ws + (BASE_) + (size_t)(FS_) * 512))[lane]; }
#define WF4(D_, BASE_, KS_) { WF(D_##0, BASE_, (KS_)*16 + fq + 0); WF(D_##1, BASE_, (KS_)*16 + fq + 1); \
                              WF(D_##2, BASE_, (KS_)*16 + fq + 2); WF(D_##3, BASE_, (KS_)*16 + fq + 3); }
#define LDA4(D_, SRC_, RS_, KB_) { const int ao_ = ((KB_) + lg * 16) ^ aswz; \
  _Pragma("unroll") for (int af_ = 0; af_ < 4; ++af_){ \
    const int r_ = af_ * 16 + lr; \
    D_[af_] = *(const short8*)((SRC_) + r_ * (RS_) + ao_); } }
#define GEMM16(W_, A_) { __builtin_amdgcn_s_setprio(1); \
  _Pragma("unroll") for (int af_ = 0; af_ < 4; ++af_){ \
    acc[0][af_] = __builtin_amdgcn_mfma_f32_16x16x32_bf16(W_##0, A_[af_], acc[0][af_], 0, 0, 0); \
    acc[1][af_] = __builtin_amdgcn_mfma_f32_16x16x32_bf16(W_##1, A_[af_], acc[1][af_], 0, 0, 0); \
    acc[2][af_] = __builtin_amdgcn_mfma_f32_16x16x32_bf16(W_##2, A_[af_], acc[2][af_], 0, 0, 0); \
    acc[3][af_] = __builtin_amdgcn_mfma_f32_16x16x32_bf16(W_##3, A_[af_], acc[3][af_], 0, 0, 0); } \
  __builtin_amdgcn_s_setprio(0); }
#define ZERO_ACC() { _Pragma("unroll") for (int i_ = 0; i_ < 4; ++i_) \
  _Pragma("unroll") for (int j_ = 0; j_ < 4; ++j_) acc[i_][j_] = (f32x4){0.f,0.f,0.f,0.f}; }
#define BAR() { asm volatile("s_waitcnt lgkmcnt(0)" ::: "memory"); \
  __builtin_amdgcn_sched_barrier(0); \
  __builtin_amdgcn_s_barrier(); \
  __builtin_amdgcn_sched_barrier(0); }
// gather staging (BM=64): thread stages row srow (0..63), 32B granule pair sq
#define LOADC(c) { const int c_ = (c); \
  int nd_ = ((c_>>1)==0)?idx4.x:((c_>>1)==1)?idx4.y:((c_>>1)==2)?idx4.z:idx4.w; \
  const size_t o_ = (size_t)nd_ * 128 + (c_ & 1) * 64 + sq * 16; \
  if (H16){ rgA = *(const short8*)(h16 + o_); rgB = *(const short8*)(h16 + o_ + 8); } \
  else { float4 qa_=*(const float4*)(h+o_), qb_=*(const float4*)(h+o_+4); \
         float4 qc_=*(const float4*)(h+o_+8), qd_=*(const float4*)(h+o_+12); \
    rgA[0]=(short)f2b(qa_.x); rgA[1]=(short)f2b(qa_.y); rgA[2]=(short)f2b(qa_.z); rgA[3]=(short)f2b(qa_.w); \
    rgA[4]=(short)f2b(qb_.x); rgA[5]=(short)f2b(qb_.y); rgA[6]=(short)f2b(qb_.z); rgA[7]=(short)f2b(qb_.w); \
    rgB[0]=(short)f2b(qc_.x); rgB[1]=(short)f2b(qc_.y); rgB[2]=(short)f2b(qc_.z); rgB[3]=(short)f2b(qc_.w); \
    rgB[4]=(short)f2b(qd_.x); rgB[5]=(short)f2b(qd_.y); rgB[6]=(short)f2b(qd_.z); rgB[7]=(short)f2b(qd_.w); } }
#define STOREC(c) { char* b_ = Zb + (((c) & 1) << 13) + srow * 128; const int sw_ = (srow & 7) << 4; \
  *(short8*)(b_ + ((sq * 32) ^ sw_))      = rgA; \
  *(short8*)(b_ + ((sq * 32 + 16) ^ sw_)) = rgB; }
// one 256-k layer, 8 k-steps, W/A 1-deep prefetch, no internal barriers
#define LAYER256(WBASE_, AB_) { \
  WF4(wfA, WBASE_, 0); \
  LDA4(afA, AB_, 512, 0); \
  _Pragma("unroll") for (int ks_ = 0; ks_ < 8; ++ks_){ \
    if (ks_ & 1){ \
      if (ks_ < 7){ WF4(wfA, WBASE_, ks_ + 1); LDA4(afA, AB_, 512, (ks_ + 1) * 64); } \
      GEMM16(wfB, afB); \
    } else { \
      WF4(wfB, WBASE_, ks_ + 1); LDA4(afB, AB_, 512, (ks_ + 1) * 64); \
      GEMM16(wfA, afA); \
    } } }

template<bool H16>
__global__ __launch_bounds__(256) void torsion_kernel(
    const float* __restrict__ h, const u16* __restrict__ h16,
    const int* __restrict__ idxs, const float* __restrict__ sb,
    const float* __restrict__ c_rb, const float* __restrict__ c_b1, const float* __restrict__ c_b2,
    const float* __restrict__ t_rb, const float* __restrict__ t_b1, const float* __restrict__ t_b2,
    const u16* __restrict__ ws, float* __restrict__ out, int NT)
{
  __shared__ __attribute__((aligned(16))) char Xb[32768];   // [64][256] bf16 swizzled
  __shared__ __attribute__((aligned(16))) char Zb[32768];   // gather dbuf 2x8KB, then Y/V

  const int tid = threadIdx.x, blk = blockIdx.x;
  const int lane = tid & 63, lr = lane & 15, lg = lane >> 4;
  const int wv = tid >> 6;                     // wave 0..3 = wn (col quarter)
  const int fq = wv * 4;
  const int aswz = (lr & 7) << 4;

  const int srow = tid >> 2, sq = tid & 3;     // staging row 0..63, granule 0..3
  const int sgrow = blk * 64 + srow;
  int4 idx4 = (sgrow < NT) ? ((const int4*)idxs)[sgrow] : (int4){0, 0, 0, 0};
  short8 rgA, rgB;
  short8 wfA0, wfA1, wfA2, wfA3, wfB0, wfB1, wfB2, wfB3;
  short8 afA[4], afB[4];

  f32x4 acc[4][4];
  ZERO_ACC();

  // ---- prologue ----
  LOADC(0); STOREC(0);
  WF4(wfA, SA_F, 0);
  BAR();
  LDA4(afA, Zb, 128, 0);

  // ================ stage A: x = elu(concat(h[idx]) @ sw.T + sb); 8 chunks ================
  #pragma unroll
  for (int c = 0; c < 8; ++c){
    const char* cb = Zb + ((c & 1) << 13);
    if (c < 7) LOADC(c + 1);
    WF4(wfB, SA_F, 2 * c + 1);
    LDA4(afB, cb, 128, 64);
    GEMM16(wfA, afA);
    if (c < 7) WF4(wfA, SA_F, 2 * c + 2);
    GEMM16(wfB, afB);
    if (c < 7) STOREC(c + 1);
    if (c == 7){
      // X epilogue: elu + bias -> Xb (swizzled bf16)
      #pragma unroll
      for (int wf = 0; wf < 4; ++wf){
        const int col0 = wv * 64 + wf * 16 + lg * 4;
        const float4 bb = *(const float4*)(sb + col0);
        #pragma unroll
        for (int af = 0; af < 4; ++af){
          const int row = af * 16 + lr;
          u32x2 pk = { packbf(elu1(acc[wf][af][0] + bb.x), elu1(acc[wf][af][1] + bb.y)),
                       packbf(elu1(acc[wf][af][2] + bb.z), elu1(acc[wf][af][3] + bb.w)) };
          *(u32x2*)(Xb + row * 512 + ((col0 * 2) ^ ((row & 7) << 4))) = pk;
        }
      }
    }
    BAR();
    if (c < 7) LDA4(afA, Zb + (((c + 1) & 1) << 13), 128, 0);
  }

  // ================ heads: c (score) then t (coeffs) ================
  f32x4 scC = (f32x4){0,0,0,0}, scT = (f32x4){0,0,0,0};
  #pragma unroll
  for (int hd = 0; hd < 2; ++hd){
    const int RWF = hd ? TRW_F : CRW_F;
    const int W1F = hd ? TW1_F : CW1_F;
    const int W2F = hd ? TW2_F : CW2_F;
    const float* RB = hd ? t_rb : c_rb;
    const float* B1 = hd ? t_b1 : c_b1;
    const float* B2 = hd ? t_b2 : c_b2;

    // ---- y = x + elu(x @ rw.T + rb) -> Zb ----
    ZERO_ACC();
    LAYER256(RWF, Xb);
    #pragma unroll
    for (int wf = 0; wf < 4; ++wf){
      const int col0 = wv * 64 + wf * 16 + lg * 4;
      const float4 bb = *(const float4*)(RB + col0);
      #pragma unroll
      for (int af = 0; af < 4; ++af){
        const int row = af * 16 + lr;
        const int boff = (col0 * 2) ^ ((row & 7) << 4);
        u32x2 xv = *(const u32x2*)(Xb + row * 512 + boff);
        float y0 = b2f((u16)(xv[0] & 0xffff)) + elu1(acc[wf][af][0] + bb.x);
        float y1 = b2f((u16)(xv[0] >> 16))    + elu1(acc[wf][af][1] + bb.y);
        float y2 = b2f((u16)(xv[1] & 0xffff)) + elu1(acc[wf][af][2] + bb.z);
        float y3 = b2f((u16)(xv[1] >> 16))    + elu1(acc[wf][af][3] + bb.w);
        u32x2 pk = { packbf(y0, y1), packbf(y2, y3) };
        *(u32x2*)(Zb + row * 512 + boff) = pk;
      }
    }
    BAR();                                  // Y visible

    // ---- v = elu(y @ w1.T + b1): layer, drain-bar, V epilogue -> Zb ----
    ZERO_ACC();
    LAYER256(W1F, Zb);
    BAR();                                  // all Y reads done before overwrite
    #pragma unroll
    for (int wf = 0; wf < 4; ++wf){
      const int col0 = wv * 64 + wf * 16 + lg * 4;
      const float4 bb = *(const float4*)(B1 + col0);
      #pragma unroll
      for (int af = 0; af < 4; ++af){
        const int row = af * 16 + lr;
        u32x2 pk = { packbf(elu1(acc[wf][af][0] + bb.x), elu1(acc[wf][af][1] + bb.y)),
                     packbf(elu1(acc[wf][af][2] + bb.z), elu1(acc[wf][af][3] + bb.w)) };
        *(u32x2*)(Zb + row * 512 + ((col0 * 2) ^ ((row & 7) << 4))) = pk;
      }
    }
    BAR();                                  // V visible

    // ---- out16 = v @ w2p.T: wave wv owns rows wv*16..+15 ----
    {
      f32x4 a1 = (f32x4){0, 0, 0, 0};
      const int vr = wv * 16 + lr;
      const int vswz = (vr & 7) << 4;
      __builtin_amdgcn_s_setprio(1);
      #pragma unroll
      for (int kt = 0; kt < 8; ++kt){
        short8 aw; WF(aw, W2F, kt);
        short8 bv = *(const short8*)(Zb + vr * 512 + ((kt * 64 + lg * 16) ^ vswz));
        a1 = __builtin_amdgcn_mfma_f32_16x16x32_bf16(aw, bv, a1, 0, 0, 0);
      }
      __builtin_amdgcn_s_setprio(0);
      #pragma unroll
      for (int r = 0; r < 4; ++r){
        const int nn = lg * 4 + r;
        a1[r] += (nn < NPER) ? B2[nn] : 0.f;
      }
      if (hd == 0) scC = a1; else scT = a1;
      BAR();                                // w2's V reads done before head t's Y overwrites
    }
  }

  // ---- epilogue: score & coeff for row (wv*16+lr) live in this lane ----
  const int grow = blk * 64 + wv * 16 + lr;
  if (grow < NT){
    #pragma unroll
    for (int r = 0; r < 4; ++r){
      const int nn = lg * 4 + r;
      if (nn < NPER){
        const float s = scC[r], c = scT[r];
        out[(size_t)grow * 6 + nn] = s;
        out[(size_t)NT * 6 + (size_t)grow * 6 + nn] = c * 1e-3f * (1.f / (1.f + __expf(-s)));
      }
    }
  }
}

extern "C" void kernel_launch(void* const* d_in, const int* in_sizes, int n_in,
                              void* d_out, int out_size, void* d_ws, size_t ws_size,
                              hipStream_t stream){
  const float* h    = (const float*)d_in[0];
  const int*   idxs = (const int*)d_in[1];
  const float* sw   = (const float*)d_in[2];
  const float* sb   = (const float*)d_in[3];
  const float* trw  = (const float*)d_in[4];
  const float* trb  = (const float*)d_in[5];
  const float* tw1  = (const float*)d_in[6];
  const float* tb1  = (const float*)d_in[7];
  const float* tw2  = (const float*)d_in[8];
  const float* tb2  = (const float*)d_in[9];
  const float* crw  = (const float*)d_in[10];
  const float* crb  = (const float*)d_in[11];
  const float* cw1  = (const float*)d_in[12];
  const float* cb1  = (const float*)d_in[13];
  const float* cw2  = (const float*)d_in[14];
  const float* cb2  = (const float*)d_in[15];
  u16* ws    = (u16*)d_ws;
  float* out = (float*)d_out;
  const int NT = in_sizes[1] / 4;
  const int nh = in_sizes[0];
  const bool useH16 = ws_size >= (size_t)(WS_WELE + nh) * 2;

  hipLaunchKernelGGL(convert_weights, dim3((WS_WELE + 255) / 256), dim3(256), 0, stream,
                     sw, crw, cw1, cw2, trw, tw1, tw2, ws);
  u16* h16 = ws + WS_WELE;
  const int nblk = (NT + 63) / 64;
  if (useH16){
    const int n8 = nh / 8;
    hipLaunchKernelGGL(convert_h, dim3((n8 + 255) / 256), dim3(256), 0, stream, h, h16, n8);
    torsion_kernel<true><<<dim3(nblk), dim3(256), 0, stream>>>(
        h, h16, idxs, sb, crb, cb1, cb2, trb, tb1, tb2, ws, out, NT);
  } else {
    torsion_kernel<false><<<dim3(nblk), dim3(256), 0, stream>>>(
        h, h16, idxs, sb, crb, cb1, cb2, trb, tb1, tb2, ws, out, NT);
  }
}